// Round 6
// baseline (3174.753 us; speedup 1.0000x reference)
//
#include <hip/hip_runtime.h>
#include <cstdint>

#define NBATCH 16
#define NPOINT 1024
#define NPTS   100000
#define GPB    16            // blocks per batch
#define TPB    256           // threads per block (4 waves)
#define WPB    4
#define NSUB   16            // sub-blocks per batch in precompute kernels
#define STRIDE (GPB * TPB)   // 4096 threads per batch
#define KPT    25            // points per thread
#define NPAIR  13            // KPT as float pairs (last half-padded)

typedef unsigned long long u64;

// d_ws layout (no host memset needed):
//   @0    : float psum[16][16][4]     (4 KB)  — per-(batch,sub) partial coord sums
//   @4096 : uint  pmax[16][16]        (1 KB)  — per-(batch,sub) partial max sq-radius
//   @8192 : u64   slots[2][16][16][4] (16 KB) — 32-B msg per (parity,batch,block):
//             w0 = seq<<54 | distbits<<22 | (0x3FFFFF - idx)
//             w1 = xbits | seq<<32      (per-word seq => tear-safe plain loads)
//             w2 = ybits | seq<<32
//             w3 = zbits | seq<<32
//           zeroed by max_kernel block 0 (poisoned w0.seq would false-accept).

// one poll round = 4 loads + ONE waitcnt = one device-coherence round trip
__device__ __forceinline__ void quad_load(const u64* p, u64& a, u64& b, u64& c, u64& d) {
    asm volatile(
        "global_load_dwordx2 %0, %4, off sc0 sc1\n\t"
        "global_load_dwordx2 %1, %4, off offset:8 sc0 sc1\n\t"
        "global_load_dwordx2 %2, %4, off offset:16 sc0 sc1\n\t"
        "global_load_dwordx2 %3, %4, off offset:24 sc0 sc1\n\t"
        "s_waitcnt vmcnt(0)"
        : "=&v"(a), "=&v"(b), "=&v"(c), "=&v"(d)
        : "v"(p) : "memory");
}

// ---------------- precompute 1: per-(batch,sub) coordinate sums ----------------
__global__ __launch_bounds__(256) void sum_kernel(const float* __restrict__ xyz,
                                                  float* __restrict__ psum) {
    const int b   = blockIdx.x & 15;
    const int sub = blockIdx.x >> 4;
    const float* P = xyz + (size_t)b * NPTS * 3;
    float sx = 0.f, sy = 0.f, sz = 0.f;
    for (int i = sub * TPB + threadIdx.x; i < NPTS; i += NSUB * TPB) {
        sx += P[i * 3 + 0];
        sy += P[i * 3 + 1];
        sz += P[i * 3 + 2];
    }
    #pragma unroll
    for (int off = 32; off; off >>= 1) {
        sx += __shfl_xor(sx, off);
        sy += __shfl_xor(sy, off);
        sz += __shfl_xor(sz, off);
    }
    __shared__ float r[3][4];
    const int wave = threadIdx.x >> 6, lane = threadIdx.x & 63;
    if (lane == 0) { r[0][wave] = sx; r[1][wave] = sy; r[2][wave] = sz; }
    __syncthreads();
    if (threadIdx.x == 0) {
        float* o = psum + (b * NSUB + sub) * 4;
        o[0] = r[0][0] + r[0][1] + r[0][2] + r[0][3];
        o[1] = r[1][0] + r[1][1] + r[1][2] + r[1][3];
        o[2] = r[2][0] + r[2][1] + r[2][2] + r[2][3];
    }
}

// -------- precompute 2: per-(batch,sub) max squared radius + slot clear --------
__global__ __launch_bounds__(256) void max_kernel(const float* __restrict__ xyz,
                                                  const float* __restrict__ psum,
                                                  unsigned* __restrict__ pmax,
                                                  u64* __restrict__ slots) {
    if (blockIdx.x == 0) {                    // clear 2048 slot words (8 per thread)
        #pragma unroll
        for (int q = 0; q < 8; ++q) slots[threadIdx.x + q * 256] = 0ull;
    }
    const int b   = blockIdx.x & 15;
    const int sub = blockIdx.x >> 4;
    const float* P = xyz + (size_t)b * NPTS * 3;
    float sx = 0.f, sy = 0.f, sz = 0.f;
    #pragma unroll
    for (int s = 0; s < NSUB; ++s) {          // fixed order: deterministic mean
        sx += psum[(b * NSUB + s) * 4 + 0];
        sy += psum[(b * NSUB + s) * 4 + 1];
        sz += psum[(b * NSUB + s) * 4 + 2];
    }
    const float mx = sx / (float)NPTS, my = sy / (float)NPTS, mz = sz / (float)NPTS;
    float best = 0.f;
    for (int i = sub * TPB + threadIdx.x; i < NPTS; i += NSUB * TPB) {
        float dx = P[i * 3 + 0] - mx;
        float dy = P[i * 3 + 1] - my;
        float dz = P[i * 3 + 2] - mz;
        best = fmaxf(best, dx * dx + dy * dy + dz * dz);
    }
    #pragma unroll
    for (int off = 32; off; off >>= 1) best = fmaxf(best, __shfl_xor(best, off));
    __shared__ float r[4];
    const int wave = threadIdx.x >> 6, lane = threadIdx.x & 63;
    if (lane == 0) r[wave] = best;
    __syncthreads();
    if (threadIdx.x == 0)
        pmax[b * NSUB + sub] = __float_as_uint(fmaxf(fmaxf(r[0], r[1]), fmaxf(r[2], r[3])));
}

// ---------------- main: FPS with coordinate-carrying messages ----------------
// Parity double-buffer, lag<=1: a seq i+3 store (same parity as i+1) requires its block
// to have finished the i+2 poll => all blocks stored i+2 => all finished the i+1 poll.
__global__ __launch_bounds__(256, 1) void fps_kernel(const float* __restrict__ xyz,
                                                     const float* __restrict__ cmap,
                                                     const int* __restrict__ init_far,
                                                     const unsigned* __restrict__ pmax,
                                                     u64* __restrict__ slots,
                                                     float* __restrict__ out) {
    const int b   = blockIdx.x & 15;   // batch (all 16 blocks of a batch on XCD b%8)
    const int g   = blockIdx.x >> 4;   // block-in-batch 0..15
    const int tid = threadIdx.x;
    const int wave = tid >> 6, lane = tid & 63;
    const int tl  = g * TPB + tid;     // batch-local lane 0..4095
    const float* P = xyz + (size_t)b * NPTS * 3;

    // s_obj: deterministic reduce over the 16 partial maxes
    float m0 = 0.f;
    #pragma unroll
    for (int s = 0; s < NSUB; ++s) m0 = fmaxf(m0, __uint_as_float(pmax[b * NSUB + s]));
    const float sb = sqrtf(m0);

    // register-resident points (pairs) + running distances
    float pxx[NPAIR], pxy[NPAIR], pyx[NPAIR], pyy[NPAIR],
          pzx[NPAIR], pzy[NPAIR], pdx[NPAIR], pdy[NPAIR];
    #pragma unroll
    for (int j = 0; j < NPAIR; ++j) {
        const int p0 = tl + (2 * j) * STRIDE;
        const int p1 = tl + (2 * j + 1) * STRIDE;
        const bool v0 = p0 < NPTS, v1 = p1 < NPTS;
        pxx[j] = v0 ? P[p0 * 3 + 0] : 0.f;  pxy[j] = v1 ? P[p1 * 3 + 0] : 0.f;
        pyx[j] = v0 ? P[p0 * 3 + 1] : 0.f;  pyy[j] = v1 ? P[p1 * 3 + 1] : 0.f;
        pzx[j] = v0 ? P[p0 * 3 + 2] : 0.f;  pzy[j] = v1 ? P[p1 * 3 + 2] : 0.f;
        pdx[j] = v0 ? 1e10f : -1.0f;        pdy[j] = v1 ? 1e10f : -1.0f;
        // every lane owns >=24 valid points -> per-lane best always >= 0
    }

    __shared__ u64   lkey[WPB];
    __shared__ float lx[WPB], ly[WPB], lz[WPB];
    __shared__ float bcx_s, bcy_s, bcz_s;
    __shared__ int   bcur_s;

    int cur = init_far[b];
    float cx = P[cur * 3 + 0], cy = P[cur * 3 + 1], cz = P[cur * 3 + 2];
    const bool wrblk = (g == 0);

    for (int i = 0; i < NPOINT; ++i) {
        if (i == NPOINT - 1) {
            if (wrblk && tid == 64) {
                float* o = out + ((size_t)b * NPOINT + i) * 4;
                o[0] = cmap[(size_t)b * NPTS + cur];
                o[1] = cx / sb; o[2] = cy / sb; o[3] = cz / sb;
            }
            break;
        }

        // ---- distance update + per-lane argmax w/ coord tracking (no fma/contract) ----
        float best = -1.0f, bx = 0.f, by = 0.f, bz = 0.f;
        int bidx = 0;
        {
            #pragma clang fp contract(off)
            #pragma unroll
            for (int j = 0; j < NPAIR; ++j) {
                float dx0 = pxx[j] - cx, dx1 = pxy[j] - cx;
                float dy0 = pyx[j] - cy, dy1 = pyy[j] - cy;
                float dz0 = pzx[j] - cz, dz1 = pzy[j] - cz;
                float s0 = dx0 * dx0 + dy0 * dy0;  float s1 = dx1 * dx1 + dy1 * dy1;
                s0 = s0 + dz0 * dz0;               s1 = s1 + dz1 * dz1;
                float n0 = fminf(pdx[j], s0);      float n1 = fminf(pdy[j], s1);
                pdx[j] = n0;                       pdy[j] = n1;
                if (n0 > best) { best = n0; bidx = tl + (2*j)   * STRIDE;
                                 bx = pxx[j]; by = pyx[j]; bz = pzx[j]; }   // strict >
                if (n1 > best) { best = n1; bidx = tl + (2*j+1) * STRIDE;
                                 bx = pxy[j]; by = pyy[j]; bz = pzy[j]; }   // => first max
            }
        }

        // ---- wave argmax: u32 dist butterfly + self-identifying winner lane ----
        const unsigned db = __float_as_uint(best);
        unsigned wm = db;
        #pragma unroll
        for (int off = 32; off; off >>= 1) {
            unsigned o2 = __shfl_xor(wm, off);
            wm = o2 > wm ? o2 : wm;
        }
        const u64 mask = __ballot(db == wm);
        bool amwin;
        if (__popcll(mask) == 1) {
            amwin = (lane == __ffsll(mask) - 1);
        } else {                         // rare exact-dist tie: min global idx wins
            int mine = (db == wm) ? bidx : 0x7FFFFFFF;
            #pragma unroll
            for (int off = 32; off; off >>= 1) mine = min(mine, __shfl_xor(mine, off));
            amwin = (db == wm) && (bidx == mine);   // bidx unique -> exactly one lane
        }
        if (amwin) {
            lkey[wave] = ((u64)wm << 22) | (u64)(0x3FFFFFu - (unsigned)bidx);
            lx[wave] = bx; ly[wave] = by; lz[wave] = bz;
        }
        __syncthreads();   // syncA

        const u64 want = (u64)(i + 1);
        const unsigned want32 = (unsigned)want;
        u64* const bs = slots + ((size_t)(i & 1) * NBATCH + b) * (GPB * 4);

        if (wave == 0) {
            // block reduce over the 4 wave keys (lanes 0..3, 2 hops)
            u64 k4 = (lane < WPB) ? lkey[lane] : 0;
            u64 bk = k4;
            #pragma unroll
            for (int off = 1; off < WPB; off <<= 1) {
                u64 o2 = __shfl_xor(bk, off);
                bk = o2 > bk ? o2 : bk;
            }
            const int wv = __ffsll(__ballot((lane < WPB) && (k4 == bk))) - 1;

            // compose + publish the 32-B message (4 agent-scope u64 stores, lanes 0..3)
            u64 msg = 0;
            if      (lane == 0) msg = bk | (want << 54);
            else if (lane == 1) msg = (u64)__float_as_uint(lx[wv]) | (want << 32);
            else if (lane == 2) msg = (u64)__float_as_uint(ly[wv]) | (want << 32);
            else if (lane == 3) msg = (u64)__float_as_uint(lz[wv]) | (want << 32);
            if (lane < 4)
                __hip_atomic_store(&bs[g * 4 + lane], msg,
                                   __ATOMIC_RELAXED, __HIP_MEMORY_SCOPE_AGENT);

            // poll: quad-load (1 waitcnt = 1 RT), per-word seq gates
            u64 w0 = 0, w1 = 0, w2 = 0, w3 = 0;
            if (lane < GPB) {
                const u64* sp = &bs[lane * 4];
                int tries = 0;
                for (;;) {
                    quad_load(sp, w0, w1, w2, w3);
                    if ((w0 >> 54) >= want &&
                        (unsigned)(w1 >> 32) == want32 &&
                        (unsigned)(w2 >> 32) == want32 &&
                        (unsigned)(w3 >> 32) == want32) break;
                    if (++tries > 16) __builtin_amdgcn_s_sleep(1);
                }
            }
            // max over the 16 gate words (4 hops reduce within each 16-lane group)
            u64 kk = w0;
            #pragma unroll
            for (int off = 1; off < GPB; off <<= 1) {
                u64 o2 = __shfl_xor(kk, off);
                kk = o2 > kk ? o2 : kk;
            }
            // winner slot's poller lane holds the payload -> writes LDS directly
            if (lane < GPB && w0 == kk) {    // idx unique across blocks -> single lane
                bcur_s = (int)(0x3FFFFFu - (unsigned)(kk & 0x3FFFFFu));
                bcx_s = __uint_as_float((unsigned)w1);
                bcy_s = __uint_as_float((unsigned)w2);
                bcz_s = __uint_as_float((unsigned)w3);
            }
        } else if (wave == 1 && wrblk && lane == 0) {
            // output row for centroid i — parallel with wave 0's store+poll
            float* o = out + ((size_t)b * NPOINT + i) * 4;
            o[0] = cmap[(size_t)b * NPTS + cur];
            o[1] = cx / sb; o[2] = cy / sb; o[3] = cz / sb;
        }
        __syncthreads();   // syncB
        cur = bcur_s;
        cx = bcx_s; cy = bcy_s; cz = bcz_s;   // coords from the message — no gather
    }
}

extern "C" void kernel_launch(void* const* d_in, const int* in_sizes, int n_in,
                              void* d_out, int out_size, void* d_ws, size_t ws_size,
                              hipStream_t stream) {
    const float* mesh = (const float*)d_in[0];
    const float* cmap = (const float*)d_in[1];
    const int* init   = (const int*)d_in[2];
    float* out = (float*)d_out;

    char* ws      = (char*)d_ws;
    float* psum   = (float*)ws;
    unsigned* pmx = (unsigned*)(ws + 4096);
    u64* slots    = (u64*)(ws + 8192);

    sum_kernel<<<dim3(256), dim3(TPB), 0, stream>>>(mesh, psum);
    max_kernel<<<dim3(256), dim3(TPB), 0, stream>>>(mesh, psum, pmx, slots);
    fps_kernel<<<dim3(256), dim3(TPB), 0, stream>>>(mesh, cmap, init, pmx, slots, out);
}

// Round 7
// 1993.560 us; speedup vs baseline: 1.5925x; 1.5925x over previous
//
#include <hip/hip_runtime.h>
#include <cstdint>

#define NBATCH 16
#define NPOINT 1024
#define NPTS   100000
#define GPB    16            // blocks per batch
#define TPB    256           // threads per block (4 waves)
#define WPB    4
#define NSUB   16            // sub-blocks per batch in precompute kernels
#define STRIDE (GPB * TPB)   // 4096 threads per batch
#define KPT    25            // points per thread
#define NPAIR  13            // KPT as float pairs (last half-padded)

typedef unsigned long long u64;

// d_ws layout (no host memset needed):
//   @0    : float psum[16][16][4]  (4 KB) — per-(batch,sub) partial coord sums (plain stores)
//   @4096 : uint  pmax[16][16]     (1 KB) — per-(batch,sub) partial max sq-radius (plain stores)
//   @8192 : u64   slots[2][16][16] (4 KB) — per-(parity,batch,block) argmax msg;
//                                           zeroed by max_kernel block 0 (poisoned seq would
//                                           false-accept, so this clear is mandatory)

// ---------------- precompute 1: per-(batch,sub) coordinate sums ----------------
__global__ __launch_bounds__(256) void sum_kernel(const float* __restrict__ xyz,
                                                  float* __restrict__ psum) {
    const int b   = blockIdx.x & 15;
    const int sub = blockIdx.x >> 4;          // 0..15
    const float* P = xyz + (size_t)b * NPTS * 3;
    float sx = 0.f, sy = 0.f, sz = 0.f;
    for (int i = sub * TPB + threadIdx.x; i < NPTS; i += NSUB * TPB) {
        sx += P[i * 3 + 0];
        sy += P[i * 3 + 1];
        sz += P[i * 3 + 2];
    }
    #pragma unroll
    for (int off = 32; off; off >>= 1) {
        sx += __shfl_xor(sx, off);
        sy += __shfl_xor(sy, off);
        sz += __shfl_xor(sz, off);
    }
    __shared__ float r[3][4];
    const int wave = threadIdx.x >> 6, lane = threadIdx.x & 63;
    if (lane == 0) { r[0][wave] = sx; r[1][wave] = sy; r[2][wave] = sz; }
    __syncthreads();
    if (threadIdx.x == 0) {
        float* o = psum + (b * NSUB + sub) * 4;
        o[0] = r[0][0] + r[0][1] + r[0][2] + r[0][3];
        o[1] = r[1][0] + r[1][1] + r[1][2] + r[1][3];
        o[2] = r[2][0] + r[2][1] + r[2][2] + r[2][3];
    }
}

// -------- precompute 2: per-(batch,sub) max squared radius + slot clear --------
__global__ __launch_bounds__(256) void max_kernel(const float* __restrict__ xyz,
                                                  const float* __restrict__ psum,
                                                  unsigned* __restrict__ pmax,
                                                  u64* __restrict__ slots) {
    if (blockIdx.x == 0) {                    // clear the 512 message slots (2 per thread)
        slots[threadIdx.x] = 0ull;
        slots[threadIdx.x + 256] = 0ull;
    }
    const int b   = blockIdx.x & 15;
    const int sub = blockIdx.x >> 4;
    const float* P = xyz + (size_t)b * NPTS * 3;
    float sx = 0.f, sy = 0.f, sz = 0.f;
    #pragma unroll
    for (int s = 0; s < NSUB; ++s) {          // fixed order: deterministic mean for all blocks
        sx += psum[(b * NSUB + s) * 4 + 0];
        sy += psum[(b * NSUB + s) * 4 + 1];
        sz += psum[(b * NSUB + s) * 4 + 2];
    }
    const float mx = sx / (float)NPTS, my = sy / (float)NPTS, mz = sz / (float)NPTS;
    float best = 0.f;
    for (int i = sub * TPB + threadIdx.x; i < NPTS; i += NSUB * TPB) {
        float dx = P[i * 3 + 0] - mx;
        float dy = P[i * 3 + 1] - my;
        float dz = P[i * 3 + 2] - mz;
        best = fmaxf(best, dx * dx + dy * dy + dz * dz);
    }
    #pragma unroll
    for (int off = 32; off; off >>= 1) best = fmaxf(best, __shfl_xor(best, off));
    __shared__ float r[4];
    const int wave = threadIdx.x >> 6, lane = threadIdx.x & 63;
    if (lane == 0) r[wave] = best;
    __syncthreads();
    if (threadIdx.x == 0)
        pmax[b * NSUB + sub] = __float_as_uint(fmaxf(fmaxf(r[0], r[1]), fmaxf(r[2], r[3])));
}

// ---------------- main: FPS loop (symmetric blocks) + deferred output pass ----------------
// Message word: [63:54] seq (=i+1), [53:22] float bits of max distance (>=0),
//               [21:0]  0x3FFFFF - idx (max-compare => smallest index on ties = np.argmax).
// Parity double-buffer, lag<=1: a seq i+3 store (same parity as i+1) requires its block
// to have finished the i+2 poll => all blocks stored i+2 => all finished the i+1 poll.
__global__ __launch_bounds__(256, 1) void fps_kernel(const float* __restrict__ xyz,
                                                     const float* __restrict__ cmap,
                                                     const int* __restrict__ init_far,
                                                     const unsigned* __restrict__ pmax,
                                                     u64* __restrict__ slots,
                                                     float* __restrict__ out) {
    const int b   = blockIdx.x & 15;   // batch (all 16 blocks of a batch on XCD b%8)
    const int g   = blockIdx.x >> 4;   // block-in-batch 0..15
    const int tid = threadIdx.x;
    const int wave = tid >> 6, lane = tid & 63;
    const int tl  = g * TPB + tid;     // batch-local lane 0..4095
    const float* P = xyz + (size_t)b * NPTS * 3;

    // s_obj: deterministic reduce over the 16 partial maxes
    float m0 = 0.f;
    #pragma unroll
    for (int s = 0; s < NSUB; ++s) m0 = fmaxf(m0, __uint_as_float(pmax[b * NSUB + s]));
    const float sb = sqrtf(m0);

    // register-resident points (pairs, SLP-vectorizes to v_pk_* fp32) + running distances
    float pxx[NPAIR], pxy[NPAIR], pyx[NPAIR], pyy[NPAIR],
          pzx[NPAIR], pzy[NPAIR], pdx[NPAIR], pdy[NPAIR];
    #pragma unroll
    for (int j = 0; j < NPAIR; ++j) {
        const int p0 = tl + (2 * j) * STRIDE;
        const int p1 = tl + (2 * j + 1) * STRIDE;
        const bool v0 = p0 < NPTS, v1 = p1 < NPTS;
        pxx[j] = v0 ? P[p0 * 3 + 0] : 0.f;  pxy[j] = v1 ? P[p1 * 3 + 0] : 0.f;
        pyx[j] = v0 ? P[p0 * 3 + 1] : 0.f;  pyy[j] = v1 ? P[p1 * 3 + 1] : 0.f;
        pzx[j] = v0 ? P[p0 * 3 + 2] : 0.f;  pzy[j] = v1 ? P[p1 * 3 + 2] : 0.f;
        pdx[j] = v0 ? 1e10f : -1.0f;        pdy[j] = v1 ? 1e10f : -1.0f;
        // every lane owns >=24 valid points -> per-lane best always >= 0
    }

    __shared__ u64 lds_key[WPB];
    __shared__ int lds_win;
    __shared__ int curhist[NPOINT];    // every block records the full selection history

    int cur = init_far[b];
    float cx = P[cur * 3 + 0], cy = P[cur * 3 + 1], cz = P[cur * 3 + 2];

    for (int i = 0; i < NPOINT; ++i) {
        if (tid == 192) curhist[i] = cur;          // off critical path (wave 3, LDS only)
        if (i == NPOINT - 1) break;

        // ---- distance update + per-lane argmax (exact fp order match: no fma/contract) ----
        float best = -1.0f;
        int bidx = 0;
        {
            #pragma clang fp contract(off)
            #pragma unroll
            for (int j = 0; j < NPAIR; ++j) {
                float dx0 = pxx[j] - cx, dx1 = pxy[j] - cx;
                float dy0 = pyx[j] - cy, dy1 = pyy[j] - cy;
                float dz0 = pzx[j] - cz, dz1 = pzy[j] - cz;
                float s0 = dx0 * dx0 + dy0 * dy0;  float s1 = dx1 * dx1 + dy1 * dy1;
                s0 = s0 + dz0 * dz0;               s1 = s1 + dz1 * dz1;
                float n0 = fminf(pdx[j], s0);      float n1 = fminf(pdy[j], s1);
                pdx[j] = n0;                       pdy[j] = n1;
                if (n0 > best) { best = n0; bidx = tl + (2 * j) * STRIDE; }      // strict >
                if (n1 > best) { best = n1; bidx = tl + (2 * j + 1) * STRIDE; }  // => first max
            }
        }

        // ---- wave argmax (u64 butterfly; inverted idx -> smallest index on ties) ----
        const u64 want = (u64)(i + 1);
        u64 key = ((u64)__float_as_uint(best) << 22) | (u64)(0x3FFFFFu - (unsigned)bidx);
        #pragma unroll
        for (int off = 32; off; off >>= 1) {
            u64 o2 = __shfl_xor(key, off);
            key = o2 > key ? o2 : key;
        }
        if (lane == 0) lds_key[wave] = key;
        __syncthreads();   // syncA

        u64* const bs = slots + ((size_t)(i & 1) * NBATCH + b) * GPB;

        if (wave == 0) {
            // block reduce (lanes 0..3, 2-hop), lane 0 publishes the slot
            u64 bk = (lane < WPB) ? lds_key[lane] : 0;
            #pragma unroll
            for (int off = 1; off < WPB; off <<= 1) {
                u64 o2 = __shfl_xor(bk, off);
                bk = o2 > bk ? o2 : bk;
            }
            if (lane == 0)
                __hip_atomic_store(&bs[g], bk | (want << 54),
                                   __ATOMIC_RELAXED, __HIP_MEMORY_SCOPE_AGENT);

            // poll: the 16 slots are one 128-B line; one atomic load + one waitcnt per round
            u64 v = 0;
            if (lane < GPB) {
                u64* sp = &bs[lane];
                int tries = 0;
                for (;;) {
                    v = __hip_atomic_load(sp, __ATOMIC_RELAXED, __HIP_MEMORY_SCOPE_AGENT);
                    if ((v >> 54) >= want) break;
                    if (++tries > 16) __builtin_amdgcn_s_sleep(1);
                }
            }
            #pragma unroll
            for (int off = 8; off; off >>= 1) {     // 4-hop argmax over the 16 gate words
                u64 o2 = __shfl_xor(v, off);
                v = o2 > v ? o2 : v;
            }
            if (lane == 0)
                lds_win = (int)(0x3FFFFFu - (unsigned)(v & 0x3FFFFFu));
        }
        __syncthreads();   // syncB
        cur = lds_win;
        cx = P[cur * 3 + 0];   // broadcast gather (L2-hot)
        cy = P[cur * 3 + 1];
        cz = P[cur * 3 + 2];
    }

    // ---------------- deferred output pass: 64 rows per block ----------------
    __syncthreads();                   // curhist fully written
    if (tid < 64) {
        const int row = g * 64 + tid;  // 16 blocks x 64 rows = 1024
        const int c   = curhist[row];
        const float cm = cmap[(size_t)b * NPTS + c];
        const float x = P[c * 3 + 0], y = P[c * 3 + 1], z = P[c * 3 + 2];
        float* o = out + ((size_t)b * NPOINT + row) * 4;
        o[0] = cm;
        o[1] = x / sb;
        o[2] = y / sb;
        o[3] = z / sb;
    }
}

extern "C" void kernel_launch(void* const* d_in, const int* in_sizes, int n_in,
                              void* d_out, int out_size, void* d_ws, size_t ws_size,
                              hipStream_t stream) {
    const float* mesh = (const float*)d_in[0];
    const float* cmap = (const float*)d_in[1];
    const int* init   = (const int*)d_in[2];
    float* out = (float*)d_out;

    char* ws      = (char*)d_ws;
    float* psum   = (float*)ws;
    unsigned* pmx = (unsigned*)(ws + 4096);
    u64* slots    = (u64*)(ws + 8192);

    sum_kernel<<<dim3(256), dim3(TPB), 0, stream>>>(mesh, psum);
    max_kernel<<<dim3(256), dim3(TPB), 0, stream>>>(mesh, psum, pmx, slots);
    fps_kernel<<<dim3(256), dim3(TPB), 0, stream>>>(mesh, cmap, init, pmx, slots, out);
}